// Round 1
// 296.185 us; speedup vs baseline: 1.0034x; 1.0034x over previous
//
#include <hip/hip_runtime.h>

// SparseEmbedding: out[b,d] = sum_n vals[b,n] * kernel[idx[b,n], d] + bias[d]
// B=4096, NNZ=32, V=1e6, D=64, fp32 (idx int32).
//
// Round 1: occupancy fix. Previous kernel launched 65536 threads = exactly
// 1 wave/SIMD (zero TLP); measured ~140us kernel time = ~0.4 B/cy/CU — near-
// total load serialization despite the 32-deep unroll. Here each row's NNZ=32
// is split across SEG=8 segments of 4 gathers: 524288 threads = 8 waves/SIMD
// (full occupancy, __launch_bounds__(256,8) caps VGPR<=64), so gather latency
// is hidden by TLP instead of hoping the compiler keeps 32 float4 results
// live. Partial sums combined via a 4KB LDS reduction (2 rows/block),
// segment-ordered for deterministic near-reference accumulation order.
//
// Per-wave gather pattern unchanged: 16 lanes x float4 = one 256B kernel row
// per 16-lane group; each wave-load covers 4 random 256B segments (16B/lane).

#define B_BATCH 4096
#define NNZ 32
#define DIM 64
#define SEG 8                 // segments per row
#define NPT (NNZ / SEG)       // 4 nnz per thread
#define ROWS_PER_BLOCK 2
#define THREADS 256           // 16 lanes * 8 segs * 2 rows

__global__ __launch_bounds__(THREADS, 8) void sparse_embed_kernel(
    const int* __restrict__ idx,
    const float* __restrict__ vals,
    const float* __restrict__ kern,
    const float* __restrict__ bias,
    float* __restrict__ out)
{
    __shared__ float4 part[THREADS];   // 4 KB

    const int tid  = threadIdx.x;
    const int lane = tid & 15;         // float4 slice of the 64-dim row
    const int seg  = (tid >> 4) & 7;   // which 4-nnz segment
    const int rloc = tid >> 7;         // row within block (0..1)
    const int row  = blockIdx.x * ROWS_PER_BLOCK + rloc;

    // This thread's 4 contiguous idx/vals (vectorized 16B loads; 16 lanes of
    // a (row,seg) group broadcast the same address — L1 absorbs it).
    const int base = row * NNZ + seg * NPT;
    const int4   i4 = *reinterpret_cast<const int4*>(idx + base);
    const float4 v4 = *reinterpret_cast<const float4*>(vals + base);

    const float* kslice = kern + (size_t)lane * 4;

    // 4 independent gathers in flight per thread; 8 waves/SIMD provide TLP.
    const float4 k0 = *reinterpret_cast<const float4*>(kslice + (size_t)i4.x * DIM);
    const float4 k1 = *reinterpret_cast<const float4*>(kslice + (size_t)i4.y * DIM);
    const float4 k2 = *reinterpret_cast<const float4*>(kslice + (size_t)i4.z * DIM);
    const float4 k3 = *reinterpret_cast<const float4*>(kslice + (size_t)i4.w * DIM);

    float4 acc;
    acc.x = v4.x * k0.x; acc.y = v4.x * k0.y; acc.z = v4.x * k0.z; acc.w = v4.x * k0.w;
    acc.x += v4.y * k1.x; acc.y += v4.y * k1.y; acc.z += v4.y * k1.z; acc.w += v4.y * k1.w;
    acc.x += v4.z * k2.x; acc.y += v4.z * k2.y; acc.z += v4.z * k2.z; acc.w += v4.z * k2.w;
    acc.x += v4.w * k3.x; acc.y += v4.w * k3.y; acc.z += v4.w * k3.z; acc.w += v4.w * k3.w;

    part[tid] = acc;
    __syncthreads();

    // seg==0 threads (16 lanes per row) fold the 8 segment partials in
    // segment order (deterministic, near-reference accumulation order).
    if (seg == 0) {
        const int pbase = rloc * 128 + lane;   // seg s partial at pbase + s*16
        float4 a = part[pbase];
        #pragma unroll
        for (int s = 1; s < SEG; ++s) {
            const float4 p = part[pbase + s * 16];
            a.x += p.x; a.y += p.y; a.z += p.z; a.w += p.w;
        }
        const float4 b4 = *reinterpret_cast<const float4*>(bias + lane * 4);
        a.x += b4.x; a.y += b4.y; a.z += b4.z; a.w += b4.w;
        *reinterpret_cast<float4*>(out + (size_t)row * DIM + lane * 4) = a;
    }
}

extern "C" void kernel_launch(void* const* d_in, const int* in_sizes, int n_in,
                              void* d_out, int out_size, void* d_ws, size_t ws_size,
                              hipStream_t stream) {
    const int*   idx  = (const int*)  d_in[0];
    const float* vals = (const float*)d_in[1];
    const float* kern = (const float*)d_in[2];
    const float* bias = (const float*)d_in[3];
    float* out = (float*)d_out;

    const int blocks = B_BATCH / ROWS_PER_BLOCK;   // 2048 blocks of 256
    sparse_embed_kernel<<<blocks, THREADS, 0, stream>>>(idx, vals, kern, bias, out);
}

// Round 2
// 295.916 us; speedup vs baseline: 1.0043x; 1.0009x over previous
//
#include <hip/hip_runtime.h>

// SparseEmbedding: out[b,d] = sum_n vals[b,n] * kernel[idx[b,n], d] + bias[d]
// B=4096, NNZ=32, V=1e6, D=64, fp32 (idx int32).
//
// Round 2: wave-per-row probe. Rounds 0 and 1 (1 wave/SIMD 32-deep unroll vs
// full-occupancy segmented+LDS) landed within 1us of each other at ~296us =>
// the timed graph is dominated by the harness's 1GB poison fill (~156us, seen
// in rocprof top-5) + tiny restore dispatches, NOT by this kernel. This round
// is the leanest possible form to (a) prove that floor and (b) restore exact
// reference accumulation order (round 1's LDS reduction reordered the sum:
// absmax 0.0 -> 0.03125).
//
// Layout: one 64-lane wave per batch row; lane d owns out[row][d]. Each
// gather-load instruction fetches exactly one 256B kernel row (64 lanes x 4B
// contiguous, perfectly coalesced). idx/vals are preloaded as int4/float4 so
// all 32 row-gathers are address-independent (up to 32 loads in flight per
// wave; 16 waves/CU of TLP on top). Accumulation is n-sequential with bias
// added last — bit-identical to the reference path (absmax 0.0 in round 0).

#define B_BATCH 4096
#define NNZ 32
#define DIM 64
#define THREADS 256   // 4 rows per block

__global__ __launch_bounds__(THREADS) void sparse_embed_kernel(
    const int* __restrict__ idx,
    const float* __restrict__ vals,
    const float* __restrict__ kern,
    const float* __restrict__ bias,
    float* __restrict__ out)
{
    const int tid = blockIdx.x * blockDim.x + threadIdx.x;
    const int row = tid >> 6;      // one wave per batch row
    const int d   = tid & 63;      // output element within the 64-dim row
    if (row >= B_BATCH) return;

    const int4*   irow = reinterpret_cast<const int4*>(idx  + row * NNZ);
    const float4* vrow = reinterpret_cast<const float4*>(vals + row * NNZ);

    // Preload all idx/vals (8x16B vector loads, wave-uniform addresses -> L1
    // broadcast) so the 32 gathers below have no address dependencies.
    int4   i4[NNZ / 4];
    float4 v4[NNZ / 4];
    #pragma unroll
    for (int c = 0; c < NNZ / 4; ++c) {
        i4[c] = irow[c];
        v4[c] = vrow[c];
    }

    // n-sequential accumulation, identical order to the reference.
    float acc = 0.f;
    #pragma unroll
    for (int c = 0; c < NNZ / 4; ++c) {
        acc += v4[c].x * kern[(size_t)i4[c].x * DIM + d];
        acc += v4[c].y * kern[(size_t)i4[c].y * DIM + d];
        acc += v4[c].z * kern[(size_t)i4[c].z * DIM + d];
        acc += v4[c].w * kern[(size_t)i4[c].w * DIM + d];
    }
    acc += bias[d];

    out[(size_t)row * DIM + d] = acc;   // 256B coalesced store per wave
}

extern "C" void kernel_launch(void* const* d_in, const int* in_sizes, int n_in,
                              void* d_out, int out_size, void* d_ws, size_t ws_size,
                              hipStream_t stream) {
    const int*   idx  = (const int*)  d_in[0];
    const float* vals = (const float*)d_in[1];
    const float* kern = (const float*)d_in[2];
    const float* bias = (const float*)d_in[3];
    float* out = (float*)d_out;

    const int total  = B_BATCH * 64;            // one lane per output element
    const int blocks = total / THREADS;         // 1024 blocks of 256
    sparse_embed_kernel<<<blocks, THREADS, 0, stream>>>(idx, vals, kern, bias, out);
}